// Round 5
// baseline (271.612 us; speedup 1.0000x reference)
//
#include <hip/hip_runtime.h>
#include <hip/hip_bf16.h>
#include <stdint.h>

#define N_ROWS 8192
#define DIM 1024
#define NUM_CLS 200
#define BM 256             // square tile edge
#define BK 32              // K-step
#define NSTEPS (DIM / BK)  // 32
#define NT2 32             // 256-tiles per dimension
#define GRID_BLOCKS (NT2 * (NT2 + 1) / 2)   // 528 upper-tri tiles

typedef __attribute__((ext_vector_type(8))) short bf16x8;
typedef __attribute__((ext_vector_type(4))) float f32x4;

__device__ __forceinline__ ushort f2bf(float f) {
    __hip_bfloat16 h = __float2bfloat16(f);
    return *reinterpret_cast<ushort*>(&h);
}

// ---------- Kernel 1: row L2-normalize, cast to bf16 (wave per row) ----------
__global__ __launch_bounds__(256) void normalize_kernel(const float* __restrict__ z,
                                                        ushort* __restrict__ zn) {
    const int row = blockIdx.x * 4 + (threadIdx.x >> 6);
    const int lane = threadIdx.x & 63;
    const float4 v = reinterpret_cast<const float4*>(z + (size_t)row * DIM)[lane];
    float ss = v.x * v.x + v.y * v.y + v.z * v.z + v.w * v.w;
    #pragma unroll
    for (int off = 1; off < 64; off <<= 1) ss += __shfl_xor(ss, off);
    const float inv = 1.0f / fmaxf(sqrtf(ss), 1e-8f);
    ushort4 o;
    o.x = f2bf(v.x * inv);
    o.y = f2bf(v.y * inv);
    o.z = f2bf(v.z * inv);
    o.w = f2bf(v.w * inv);
    reinterpret_cast<ushort4*>(zn + (size_t)row * DIM)[lane] = o;
}

// ---------- Kernel 2: fused Gram + exp + masked row sums ----------
// 256x256 tile, 8 waves (2x4), BK=32. 3-slot LDS ring (96KB): stage K-step
// t+2 during compute of t; counted s_waitcnt vmcnt(4) + raw s_barrier per
// step (loads stay in flight across barriers — no drain-0 lockstep).
// Overwrite safety is barrier-only: slot(t+2)'s last reader was step t-1.
__global__ __launch_bounds__(512, 1) void gram_kernel(const ushort* __restrict__ zn,
                                                      const int* __restrict__ labels,
                                                      float* __restrict__ row_same,
                                                      float* __restrict__ row_diff) {
    // flat upper-triangular decode, row-major: consecutive blocks share A-panel
    int rem = blockIdx.x, bi = 0, len = NT2;
    while (rem >= len) { rem -= len; ++bi; --len; }
    const int bj = bi + rem;
    const bool diag = (bi == bj);

    const int r0 = bi * BM, c0 = bj * BM;
    const int t = threadIdx.x;
    const int lane = t & 63, wv = t >> 6;   // 8 waves
    const int wr = wv >> 2, wc = wv & 3;    // 2 x 4 wave grid

    __shared__ ushort sA[3][BM * BK];    // 3 x 16 KB
    __shared__ ushort sB[3][BM * BK];    // 3 x 16 KB  (total 96 KB)

    f32x4 acc[8][4];
    #pragma unroll
    for (int m = 0; m < 8; m++)
        #pragma unroll
        for (int n = 0; n < 4; n++) acc[m][n] = (f32x4){0.f, 0.f, 0.f, 0.f};

    // Stage one BK-slice of A and B into ring slot `buf`.
    // LDS dest linear; global source slot inverse-swizzled (rule #21 pair).
    auto stage = [&](int buf, int kt) {
        #pragma unroll
        for (int h = 0; h < 2; h++) {
            const int c = h * 512 + t;          // 0..1023 chunks of 16B
            const int r = c >> 2;               // row 0..255
            const int sp = c & 3;               // LDS slot
            const int rr = (r + (r >> 2)) & 3;
            const int s = (sp - rr) & 3;        // global slot
            const ushort* gA = zn + (size_t)(r0 + r) * DIM + kt + s * 8;
            __builtin_amdgcn_global_load_lds(
                (const __attribute__((address_space(1))) uint32_t*)gA,
                (__attribute__((address_space(3))) uint32_t*)&sA[buf][c * 8],
                16, 0, 0);
            const ushort* gB = zn + (size_t)(c0 + r) * DIM + kt + s * 8;
            __builtin_amdgcn_global_load_lds(
                (const __attribute__((address_space(1))) uint32_t*)gB,
                (__attribute__((address_space(3))) uint32_t*)&sB[buf][c * 8],
                16, 0, 0);
        }
    };

    const int rbase = wr * 128 + (lane & 15);
    const int cbase = wc * 64 + (lane & 15);
    const int sidx = lane >> 4;              // k-slot 0..3

    // Prologue: slots 0 and 1 in flight; wait slot 0 landed (4 newest fly).
    stage(0, 0);
    stage(1, BK);
    asm volatile("s_waitcnt vmcnt(4)" ::: "memory");
    __builtin_amdgcn_s_barrier();
    __builtin_amdgcn_sched_barrier(0);

    for (int it = 0; it < NSTEPS; ++it) {
        const int slot = it % 3;
        if (it + 2 < NSTEPS) stage((it + 2) % 3, (it + 2) * BK);

        const ushort* __restrict__ pA = sA[slot];
        const ushort* __restrict__ pB = sB[slot];
        bf16x8 a[4], b[4];
        // phase 1: A rows m=0..3 + all B frags
        #pragma unroll
        for (int x = 0; x < 4; x++) {
            const int row = rbase + x * 16;
            const int sp = (sidx + row + (row >> 2)) & 3;
            a[x] = *reinterpret_cast<const bf16x8*>(&pA[row * 32 + sp * 8]);
            const int rowb = cbase + x * 16;
            const int spb = (sidx + rowb + (rowb >> 2)) & 3;
            b[x] = *reinterpret_cast<const bf16x8*>(&pB[rowb * 32 + spb * 8]);
        }
        __builtin_amdgcn_s_setprio(1);
        #pragma unroll
        for (int m = 0; m < 4; m++)
            #pragma unroll
            for (int n = 0; n < 4; n++)
                acc[m][n] = __builtin_amdgcn_mfma_f32_16x16x32_bf16(
                    a[m], b[n], acc[m][n], 0, 0, 0);
        __builtin_amdgcn_s_setprio(0);

        // phase 2: A rows m=4..7 (reuse B)
        #pragma unroll
        for (int x = 0; x < 4; x++) {
            const int row = rbase + (x + 4) * 16;
            const int sp = (sidx + row + (row >> 2)) & 3;
            a[x] = *reinterpret_cast<const bf16x8*>(&pA[row * 32 + sp * 8]);
        }
        __builtin_amdgcn_s_setprio(1);
        #pragma unroll
        for (int m = 0; m < 4; m++)
            #pragma unroll
            for (int n = 0; n < 4; n++)
                acc[m + 4][n] = __builtin_amdgcn_mfma_f32_16x16x32_bf16(
                    a[m], b[n], acc[m + 4][n], 0, 0, 0);
        __builtin_amdgcn_s_setprio(0);

        // counted wait: next slot's loads landed; newest 4 stay in flight
        if (it + 2 < NSTEPS) {
            asm volatile("s_waitcnt vmcnt(4)" ::: "memory");
        } else if (it + 1 < NSTEPS) {
            asm volatile("s_waitcnt vmcnt(0)" ::: "memory");
        }
        __builtin_amdgcn_s_barrier();
        __builtin_amdgcn_sched_barrier(0);
    }

    __syncthreads();   // full drain + fence before LDS reuse

    // ---- labels into reused LDS ----
    int* labR = (int*)&sA[0][0];
    int* labC = labR + 256;
    if (t < 256) labR[t] = labels[r0 + t];
    else if (t < 512) labC[t - 256] = labels[c0 + (t - 256)];
    __syncthreads();

    // ---- Epilogue: exp + masked sums. C/D: col=lane&15, row=(lane>>4)*4+q ----
    float cs[4] = {0.f, 0.f, 0.f, 0.f}, cd[4] = {0.f, 0.f, 0.f, 0.f};
    #pragma unroll
    for (int m = 0; m < 8; m++) {
        #pragma unroll
        for (int q = 0; q < 4; q++) {
            const int ii = wr * 128 + m * 16 + (lane >> 4) * 4 + q;
            const int li = labR[ii];
            float vs = 0.f, vd = 0.f;
            #pragma unroll
            for (int n = 0; n < 4; n++) {
                const int jj = wc * 64 + n * 16 + (lane & 15);
                const float e = __expf(acc[m][n][q]);
                const bool same = (li == labC[jj]);
                if (!diag || ii != jj) {
                    if (same) { vs += e; if (!diag) cs[n] += e; }
                    else      { vd += e; if (!diag) cd[n] += e; }
                }
            }
            #pragma unroll
            for (int off = 1; off < 16; off <<= 1) {
                vs += __shfl_xor(vs, off);
                vd += __shfl_xor(vd, off);
            }
            if ((lane & 15) == 0) {
                atomicAdd(&row_same[r0 + ii], vs);
                atomicAdd(&row_diff[r0 + ii], vd);
            }
        }
    }

    // column sums (symmetry contribution), off-diagonal tiles only
    if (!diag) {
        #pragma unroll
        for (int n = 0; n < 4; n++) {
            float vs = cs[n], vd = cd[n];
            vs += __shfl_xor(vs, 16); vd += __shfl_xor(vd, 16);
            vs += __shfl_xor(vs, 32); vd += __shfl_xor(vd, 32);
            if (lane < 16) {
                const int j = c0 + wc * 64 + n * 16 + lane;
                atomicAdd(&row_same[j], vs);
                atomicAdd(&row_diff[j], vd);
            }
        }
    }
}

// ---------- Kernel 3a: per-block class partial sums ----------
__global__ __launch_bounds__(256) void class_sum_kernel(const int* __restrict__ labels,
                                                        const float* __restrict__ row_same,
                                                        const float* __restrict__ row_diff,
                                                        float* __restrict__ cls_same,
                                                        float* __restrict__ cls_diff,
                                                        int* __restrict__ cls_cnt) {
    __shared__ float ls[NUM_CLS], ld_[NUM_CLS];
    __shared__ int lc[NUM_CLS];
    const int t = threadIdx.x;
    for (int c = t; c < NUM_CLS; c += 256) { ls[c] = 0.f; ld_[c] = 0.f; lc[c] = 0; }
    __syncthreads();
    const int r = blockIdx.x * 256 + t;
    if (r < N_ROWS) {
        const int l = labels[r];
        atomicAdd(&ls[l], row_same[r]);
        atomicAdd(&ld_[l], row_diff[r]);
        atomicAdd(&lc[l], 1);
    }
    __syncthreads();
    for (int c = t; c < NUM_CLS; c += 256) {
        if (lc[c] > 0) {
            atomicAdd(&cls_same[c], ls[c]);
            atomicAdd(&cls_diff[c], ld_[c]);
            atomicAdd(&cls_cnt[c], lc[c]);
        }
    }
}

// ---------- Kernel 3b: final scalar ----------
__global__ __launch_bounds__(256) void final_kernel(const float* __restrict__ cls_same,
                                                    const float* __restrict__ cls_diff,
                                                    const int* __restrict__ cls_cnt,
                                                    float* __restrict__ out) {
    const int t = threadIdx.x;
    float p = 0.f;
    if (t < NUM_CLS && cls_cnt[t] > 0) p = logf(cls_same[t] / cls_diff[t]);
    #pragma unroll
    for (int off = 1; off < 64; off <<= 1) p += __shfl_xor(p, off);
    __shared__ float wsum[4];
    if ((t & 63) == 0) wsum[t >> 6] = p;
    __syncthreads();
    if (t == 0) out[0] = (wsum[0] + wsum[1] + wsum[2] + wsum[3]) / 128.0f;
}

extern "C" void kernel_launch(void* const* d_in, const int* in_sizes, int n_in,
                              void* d_out, int out_size, void* d_ws, size_t ws_size,
                              hipStream_t stream) {
    const float* z = (const float*)d_in[1];       // semantic_embeddings
    const int* labels = (const int*)d_in[3];      // labels

    ushort* zn = (ushort*)d_ws;                                   // 16 MB bf16
    char* p = (char*)d_ws + (size_t)N_ROWS * DIM * 2;
    float* row_same = (float*)p;                 p += N_ROWS * sizeof(float);
    float* row_diff = (float*)p;                 p += N_ROWS * sizeof(float);
    float* cls_same = (float*)p;                 p += 256 * sizeof(float);
    float* cls_diff = (float*)p;                 p += 256 * sizeof(float);
    int*   cls_cnt  = (int*)p;

    hipMemsetAsync(row_same, 0,
                   (2 * N_ROWS + 2 * 256) * sizeof(float) + 256 * sizeof(int),
                   stream);

    normalize_kernel<<<N_ROWS / 4, 256, 0, stream>>>(z, zn);

    gram_kernel<<<GRID_BLOCKS, 512, 0, stream>>>(zn, labels, row_same, row_diff);

    class_sum_kernel<<<N_ROWS / 256, 256, 0, stream>>>(labels, row_same, row_diff,
                                                       cls_same, cls_diff, cls_cnt);
    final_kernel<<<1, 256, 0, stream>>>(cls_same, cls_diff, cls_cnt, (float*)d_out);
}

// Round 6
// 257.221 us; speedup vs baseline: 1.0559x; 1.0559x over previous
//
#include <hip/hip_runtime.h>
#include <hip/hip_bf16.h>
#include <stdint.h>

#define N_ROWS 8192
#define DIM 1024
#define NUM_CLS 200
#define BM 256             // square tile edge
#define BK 64              // K-tile depth
#define NKT (DIM / BK)     // 16 K-tiles
#define NT2 32             // 256-tiles per dimension
#define NSUP 10            // upper-tri supertiles of 8x8 tiles
#define GRID_BLOCKS (NSUP * 64)

typedef __attribute__((ext_vector_type(8))) short bf16x8;
typedef __attribute__((ext_vector_type(4))) float f32x4;

__device__ __forceinline__ ushort f2bf(float f) {
    __hip_bfloat16 h = __float2bfloat16(f);
    return *reinterpret_cast<ushort*>(&h);
}

// ---------- Kernel 1: row L2-normalize, cast to bf16 (wave per row) ----------
__global__ __launch_bounds__(256) void normalize_kernel(const float* __restrict__ z,
                                                        ushort* __restrict__ zn) {
    const int row = blockIdx.x * 4 + (threadIdx.x >> 6);
    const int lane = threadIdx.x & 63;
    const float4 v = reinterpret_cast<const float4*>(z + (size_t)row * DIM)[lane];
    float ss = v.x * v.x + v.y * v.y + v.z * v.z + v.w * v.w;
    #pragma unroll
    for (int off = 1; off < 64; off <<= 1) ss += __shfl_xor(ss, off);
    const float inv = 1.0f / fmaxf(sqrtf(ss), 1e-8f);
    ushort4 o;
    o.x = f2bf(v.x * inv);
    o.y = f2bf(v.y * inv);
    o.z = f2bf(v.z * inv);
    o.w = f2bf(v.w * inv);
    reinterpret_cast<ushort4*>(zn + (size_t)row * DIM)[lane] = o;
}

// ---------- Kernel 2: fused Gram + exp + masked row sums, 8-phase ----------
// m201-style schedule: BK=64 K-tiles, 4 sub-phases each {ds_read subtile,
// stage 1 half-tile (2 gload_lds), barrier, lgkmcnt(0), setprio, 16 MFMA,
// setprio, barrier}; counted vmcnt(4) once per K-tile (never 0 mid-loop).
// Staging safety: each region staged >=1 end-barrier after its last reader.
__global__ __launch_bounds__(512, 1) void gram_kernel(const ushort* __restrict__ zn,
                                                      const int* __restrict__ labels,
                                                      float* __restrict__ row_same,
                                                      float* __restrict__ row_diff) {
    constexpr int SBi[NSUP] = {0, 0, 1, 0, 1, 2, 0, 1, 2, 3};
    constexpr int SBj[NSUP] = {0, 1, 1, 2, 2, 2, 3, 3, 3, 3};

    const int st = blockIdx.x >> 6;      // 0..9
    const int p = blockIdx.x & 63;
    const int xcd = p & 7;               // round-robin XCD slot
    const int idx = p >> 3;              // 0..7 within slab
    const int bi_l = (xcd & 3) * 2 + (idx >> 2);   // 0..7
    const int bj_l = (xcd >> 2) * 4 + (idx & 3);   // 0..7
    const int bi = SBi[st] * 8 + bi_l;
    const int bj = SBj[st] * 8 + bj_l;
    if (bi > bj) return;                 // block-uniform, before any sync
    const bool diag = (bi == bj);

    const int r0 = bi * BM, c0 = bj * BM;
    const int t = threadIdx.x;
    const int lane = t & 63, wv = t >> 6;   // 8 waves
    const int wr = wv >> 2, wc = wv & 3;    // 2 x 4 wave grid
    const int lrow = lane & 15;
    const int lgrp = lane >> 4;             // 0..3

    // [buf][mat(A=0,B=1)][row 0..255][8 slots x 8 bf16] = 128 KB
    __shared__ ushort lds[2 * 2 * 256 * 64];

    f32x4 acc[8][4];
    #pragma unroll
    for (int m = 0; m < 8; m++)
        #pragma unroll
        for (int n = 0; n < 4; n++) acc[m][n] = (f32x4){0.f, 0.f, 0.f, 0.f};

    // Stage one half-tile (128 rows x 64 cols, 16 KB): 2 gload_lds/thread.
    // region: 0=B0,1=B1,2=A0,3=A1. LDS dest linear; global source slot
    // inverse-swizzled: physical slot sp holds global slot (sp - r - r>>3)&7.
    auto stage = [&](int kt, int region) {
        const int buf = kt & 1;
        const int mat = (region >= 2) ? 0 : 1;
        const int half = region & 1;
        const size_t grow = (size_t)((mat == 0 ? r0 : c0) + half * 128);
        ushort* ldst = &lds[(size_t)((buf * 2 + mat) * 256 + half * 128) * 64];
        #pragma unroll
        for (int hh = 0; hh < 2; hh++) {
            const int c = hh * 512 + t;      // 0..1023 chunks of 16B
            const int r = c >> 3;            // 0..127 row within half
            const int sp = c & 7;            // physical slot
            const int s = (sp - r - (r >> 3)) & 7;   // global slot
            const ushort* g = zn + (grow + r) * DIM + kt * BK + s * 8;
            __builtin_amdgcn_global_load_lds(
                (const __attribute__((address_space(1))) uint32_t*)g,
                (__attribute__((address_space(3))) uint32_t*)&ldst[(size_t)c * 8],
                16, 0, 0);
        }
    };

    // Prologue: kt0 + kt1 fully staged (8 half-tiles, 16 loads/thread).
    #pragma unroll
    for (int kt = 0; kt < 2; kt++)
        #pragma unroll
        for (int rg = 0; rg < 4; rg++) stage(kt, rg);
    asm volatile("s_waitcnt vmcnt(8)" ::: "memory");  // kt0 landed; kt1 may fly
    __builtin_amdgcn_s_barrier();

    bf16x8 a[4][2], b[4][2];

    for (int kc = 0; kc < NKT; ++kc) {
        const int buf = kc & 1;
        const ushort* pA = &lds[(size_t)(buf * 2 + 0) * 256 * 64];
        const ushort* pB = &lds[(size_t)(buf * 2 + 1) * 256 * 64];

        auto rd = [&](const ushort* pM, int R, int ks) -> bf16x8 {
            const int r = R & 127;
            const int sp = ((ks * 4 + lgrp) + r + (r >> 3)) & 7;
            return *reinterpret_cast<const bf16x8*>(&pM[R * 64 + sp * 8]);
        };

        // ---- sub-phase 0: read A[m0-3] + B[n0-1]; stage A0 of kt+1 ----
        #pragma unroll
        for (int m = 0; m < 4; m++) {
            a[m][0] = rd(pA, wr * 128 + m * 16 + lrow, 0);
            a[m][1] = rd(pA, wr * 128 + m * 16 + lrow, 1);
        }
        #pragma unroll
        for (int n = 0; n < 2; n++) {
            b[n][0] = rd(pB, wc * 64 + n * 16 + lrow, 0);
            b[n][1] = rd(pB, wc * 64 + n * 16 + lrow, 1);
        }
        if (kc >= 1 && kc <= 14) stage(kc + 1, 2);
        __builtin_amdgcn_s_barrier();
        asm volatile("s_waitcnt lgkmcnt(0)" ::: "memory");
        __builtin_amdgcn_sched_barrier(0);
        __builtin_amdgcn_s_setprio(1);
        #pragma unroll
        for (int m = 0; m < 4; m++)
            #pragma unroll
            for (int n = 0; n < 2; n++)
                #pragma unroll
                for (int ks = 0; ks < 2; ks++)
                    acc[m][n] = __builtin_amdgcn_mfma_f32_16x16x32_bf16(
                        a[m][ks], b[n][ks], acc[m][n], 0, 0, 0);
        __builtin_amdgcn_s_setprio(0);
        __builtin_amdgcn_s_barrier();

        // ---- sub-phase 1: read B[n2-3]; stage A1 of kt+1 ----
        #pragma unroll
        for (int n = 2; n < 4; n++) {
            b[n][0] = rd(pB, wc * 64 + n * 16 + lrow, 0);
            b[n][1] = rd(pB, wc * 64 + n * 16 + lrow, 1);
        }
        if (kc >= 1 && kc <= 14) stage(kc + 1, 3);
        __builtin_amdgcn_s_barrier();
        asm volatile("s_waitcnt lgkmcnt(0)" ::: "memory");
        __builtin_amdgcn_sched_barrier(0);
        __builtin_amdgcn_s_setprio(1);
        #pragma unroll
        for (int m = 0; m < 4; m++)
            #pragma unroll
            for (int n = 2; n < 4; n++)
                #pragma unroll
                for (int ks = 0; ks < 2; ks++)
                    acc[m][n] = __builtin_amdgcn_mfma_f32_16x16x32_bf16(
                        a[m][ks], b[n][ks], acc[m][n], 0, 0, 0);
        __builtin_amdgcn_s_setprio(0);
        __builtin_amdgcn_s_barrier();

        // ---- sub-phase 2: read A[m4-7]; stage B0 of kt+2 ----
        #pragma unroll
        for (int m = 0; m < 4; m++) {
            a[m][0] = rd(pA, wr * 128 + (m + 4) * 16 + lrow, 0);
            a[m][1] = rd(pA, wr * 128 + (m + 4) * 16 + lrow, 1);
        }
        if (kc <= 13) stage(kc + 2, 0);
        __builtin_amdgcn_s_barrier();
        asm volatile("s_waitcnt lgkmcnt(0)" ::: "memory");
        __builtin_amdgcn_sched_barrier(0);
        __builtin_amdgcn_s_setprio(1);
        #pragma unroll
        for (int m = 0; m < 4; m++)
            #pragma unroll
            for (int n = 0; n < 2; n++)
                #pragma unroll
                for (int ks = 0; ks < 2; ks++)
                    acc[m + 4][n] = __builtin_amdgcn_mfma_f32_16x16x32_bf16(
                        a[m][ks], b[n][ks], acc[m + 4][n], 0, 0, 0);
        __builtin_amdgcn_s_setprio(0);
        __builtin_amdgcn_s_barrier();

        // ---- sub-phase 3: no reads; stage B1 of kt+2; counted vmcnt ----
        if (kc <= 13) stage(kc + 2, 1);
        __builtin_amdgcn_s_barrier();
        __builtin_amdgcn_s_setprio(1);
        #pragma unroll
        for (int m = 0; m < 4; m++)
            #pragma unroll
            for (int n = 2; n < 4; n++)
                #pragma unroll
                for (int ks = 0; ks < 2; ks++)
                    acc[m + 4][n] = __builtin_amdgcn_mfma_f32_16x16x32_bf16(
                        a[m][ks], b[n][ks], acc[m + 4][n], 0, 0, 0);
        __builtin_amdgcn_s_setprio(0);
        // Guard next K-tile's reads: allow only the 2 newest stage events
        // (4 loads) to remain in flight. kc=14: next events don't exist ->
        // full drain. kc=15: nothing follows; epilogue syncthreads drains.
        if (kc <= 13) {
            asm volatile("s_waitcnt vmcnt(4)" ::: "memory");
        } else if (kc == 14) {
            asm volatile("s_waitcnt vmcnt(0)" ::: "memory");
        }
        __builtin_amdgcn_s_barrier();
    }

    __syncthreads();   // full drain + fence before LDS reuse

    // ---- labels into reused LDS ----
    int* labR = (int*)&lds[0];
    int* labC = labR + 256;
    if (t < 256) labR[t] = labels[r0 + t];
    else if (t < 512) labC[t - 256] = labels[c0 + (t - 256)];
    __syncthreads();

    // ---- Epilogue: exp + masked sums. C/D: col=lane&15, row=(lane>>4)*4+q ----
    float cs[4] = {0.f, 0.f, 0.f, 0.f}, cd[4] = {0.f, 0.f, 0.f, 0.f};
    #pragma unroll
    for (int m = 0; m < 8; m++) {
        #pragma unroll
        for (int q = 0; q < 4; q++) {
            const int ii = wr * 128 + m * 16 + (lane >> 4) * 4 + q;
            const int li = labR[ii];
            float vs = 0.f, vd = 0.f;
            #pragma unroll
            for (int n = 0; n < 4; n++) {
                const int jj = wc * 64 + n * 16 + (lane & 15);
                const float e = __expf(acc[m][n][q]);
                const bool same = (li == labC[jj]);
                if (!diag || ii != jj) {
                    if (same) { vs += e; if (!diag) cs[n] += e; }
                    else      { vd += e; if (!diag) cd[n] += e; }
                }
            }
            #pragma unroll
            for (int off = 1; off < 16; off <<= 1) {
                vs += __shfl_xor(vs, off);
                vd += __shfl_xor(vd, off);
            }
            if ((lane & 15) == 0) {
                atomicAdd(&row_same[r0 + ii], vs);
                atomicAdd(&row_diff[r0 + ii], vd);
            }
        }
    }

    // column sums (symmetry contribution), off-diagonal tiles only
    if (!diag) {
        #pragma unroll
        for (int n = 0; n < 4; n++) {
            float vs = cs[n], vd = cd[n];
            vs += __shfl_xor(vs, 16); vd += __shfl_xor(vd, 16);
            vs += __shfl_xor(vs, 32); vd += __shfl_xor(vd, 32);
            if (lane < 16) {
                const int j = c0 + wc * 64 + n * 16 + lane;
                atomicAdd(&row_same[j], vs);
                atomicAdd(&row_diff[j], vd);
            }
        }
    }
}

// ---------- Kernel 3a: per-block class partial sums ----------
__global__ __launch_bounds__(256) void class_sum_kernel(const int* __restrict__ labels,
                                                        const float* __restrict__ row_same,
                                                        const float* __restrict__ row_diff,
                                                        float* __restrict__ cls_same,
                                                        float* __restrict__ cls_diff,
                                                        int* __restrict__ cls_cnt) {
    __shared__ float ls[NUM_CLS], ld_[NUM_CLS];
    __shared__ int lc[NUM_CLS];
    const int t = threadIdx.x;
    for (int c = t; c < NUM_CLS; c += 256) { ls[c] = 0.f; ld_[c] = 0.f; lc[c] = 0; }
    __syncthreads();
    const int r = blockIdx.x * 256 + t;
    if (r < N_ROWS) {
        const int l = labels[r];
        atomicAdd(&ls[l], row_same[r]);
        atomicAdd(&ld_[l], row_diff[r]);
        atomicAdd(&lc[l], 1);
    }
    __syncthreads();
    for (int c = t; c < NUM_CLS; c += 256) {
        if (lc[c] > 0) {
            atomicAdd(&cls_same[c], ls[c]);
            atomicAdd(&cls_diff[c], ld_[c]);
            atomicAdd(&cls_cnt[c], lc[c]);
        }
    }
}

// ---------- Kernel 3b: final scalar ----------
__global__ __launch_bounds__(256) void final_kernel(const float* __restrict__ cls_same,
                                                    const float* __restrict__ cls_diff,
                                                    const int* __restrict__ cls_cnt,
                                                    float* __restrict__ out) {
    const int t = threadIdx.x;
    float p = 0.f;
    if (t < NUM_CLS && cls_cnt[t] > 0) p = logf(cls_same[t] / cls_diff[t]);
    #pragma unroll
    for (int off = 1; off < 64; off <<= 1) p += __shfl_xor(p, off);
    __shared__ float wsum[4];
    if ((t & 63) == 0) wsum[t >> 6] = p;
    __syncthreads();
    if (t == 0) out[0] = (wsum[0] + wsum[1] + wsum[2] + wsum[3]) / 128.0f;
}

extern "C" void kernel_launch(void* const* d_in, const int* in_sizes, int n_in,
                              void* d_out, int out_size, void* d_ws, size_t ws_size,
                              hipStream_t stream) {
    const float* z = (const float*)d_in[1];       // semantic_embeddings
    const int* labels = (const int*)d_in[3];      // labels

    ushort* zn = (ushort*)d_ws;                                   // 16 MB bf16
    char* p = (char*)d_ws + (size_t)N_ROWS * DIM * 2;
    float* row_same = (float*)p;                 p += N_ROWS * sizeof(float);
    float* row_diff = (float*)p;                 p += N_ROWS * sizeof(float);
    float* cls_same = (float*)p;                 p += 256 * sizeof(float);
    float* cls_diff = (float*)p;                 p += 256 * sizeof(float);
    int*   cls_cnt  = (int*)p;

    hipMemsetAsync(row_same, 0,
                   (2 * N_ROWS + 2 * 256) * sizeof(float) + 256 * sizeof(int),
                   stream);

    normalize_kernel<<<N_ROWS / 4, 256, 0, stream>>>(z, zn);

    gram_kernel<<<GRID_BLOCKS, 512, 0, stream>>>(zn, labels, row_same, row_diff);

    class_sum_kernel<<<N_ROWS / 256, 256, 0, stream>>>(labels, row_same, row_diff,
                                                       cls_same, cls_diff, cls_cnt);
    final_kernel<<<1, 256, 0, stream>>>(cls_same, cls_diff, cls_cnt, (float*)d_out);
}